// Round 9
// baseline (252.727 us; speedup 1.0000x reference)
//
#include <hip/hip_runtime.h>
#include <math.h>

#define NN     100000
#define NE     1200000
#define D      64
#define BN_EPS 1e-5f
#define CHUNK  8192
#define NCHUNK ((NE + CHUNK - 1) / CHUNK)    // 147
#define NB     ((NN + 511) / 512)            // 196 buckets of 512 nodes
#define CAPD   8192                          // fixed capacity per bucket
#define NCVT   (NN * 16 / 256)               // 6250 cvt blocks

__device__ __forceinline__ float bcastf(float v, int srcLane) {
    return __int_as_float(__builtin_amdgcn_readlane(__float_as_int(v), srcLane));
}
__device__ __forceinline__ unsigned bf16rne(float f) {
    unsigned u = __float_as_uint(f);
    return (u + 0x7FFFu + ((u >> 16) & 1u)) >> 16;
}
__device__ __forceinline__ void acc_bf16(float4& acc, uint2 a) {
    acc.x += __uint_as_float(a.x << 16);
    acc.y += __uint_as_float(a.x & 0xffff0000u);
    acc.z += __uint_as_float(a.y << 16);
    acc.w += __uint_as_float(a.y & 0xffff0000u);
}
// exclusive prefix of s across 256 threads (all threads must call).
__device__ __forceinline__ int block_scan_excl(int s, int* wsum, int* wexc) {
    const int lane = threadIdx.x & 63, wid = threadIdx.x >> 6;
    int incl = s;
    #pragma unroll
    for (int off = 1; off < 64; off <<= 1) {
        int n = __shfl_up(incl, off, 64);
        if (lane >= off) incl += n;
    }
    if (lane == 63) wsum[wid] = incl;
    __syncthreads();
    if (threadIdx.x == 0) {
        int r = 0;
        #pragma unroll
        for (int w = 0; w < 4; ++w) { wexc[w] = r; r += wsum[w]; }
    }
    __syncthreads();
    return wexc[wid] + incl - s;
}

// ---------------------------------------------------------------------------
// K1 (fused, block-specialized): blocks [0,NCVT) convert x f32->bf16.
// Blocks [NCVT, NCVT+NCHUNK): per-chunk LDS histogram -> local bucket sort
// in LDS -> reserve per-bucket space via ONE global atomicAdd per touched
// bucket -> write bucket-contiguous runs into fixed-capacity regions
// srcSorted[b*CAPD ...].
// ---------------------------------------------------------------------------
__global__ __launch_bounds__(256) void cvt_binsort_kernel(
        const float4* __restrict__ xv, uint2* __restrict__ xb,
        const int* __restrict__ src, const int* __restrict__ dst,
        int* __restrict__ cursor, int* __restrict__ binned) {
    const int tid = threadIdx.x;
    if (blockIdx.x < NCVT) {
        const int gid = blockIdx.x * 256 + tid;      // over NN*16 exact
        float4 v = xv[gid];
        uint2 o;
        o.x = bf16rne(v.x) | (bf16rne(v.y) << 16);
        o.y = bf16rne(v.z) | (bf16rne(v.w) << 16);
        xb[gid] = o;
        return;
    }
    __shared__ int histEx[256];          // counts, then local exclusive base
    __shared__ int lcur[256];
    __shared__ int gbase[256];
    __shared__ int sorted[CHUNK];        // 32 KB
    __shared__ unsigned char bOf[CHUNK]; // 8 KB
    __shared__ int wsum[4], wexc[4];
    const int i = blockIdx.x - NCVT;     // chunk id
    const int e0 = i * CHUNK;
    const int n = min(CHUNK, NE - e0);

    histEx[tid] = 0;
    __syncthreads();
    for (int k = tid; k < n; k += 256)
        atomicAdd(&histEx[dst[e0 + k] >> 9], 1);
    __syncthreads();
    const int cnt = histEx[tid];                     // own slot
    const int ex = block_scan_excl(cnt, wsum, wexc);
    histEx[tid] = ex;
    lcur[tid] = ex;
    if (tid < NB && cnt > 0)
        gbase[tid] = atomicAdd(&cursor[tid], cnt);   // reserve run space
    __syncthreads();
    for (int k = tid; k < n; k += 256) {
        const int dv = dst[e0 + k];
        const int b = dv >> 9;
        const int slot = atomicAdd(&lcur[b], 1);
        sorted[slot] = (src[e0 + k] << 9) | (dv & 511);
        bOf[slot] = (unsigned char)b;
    }
    __syncthreads();
    for (int k = tid; k < n; k += 256) {
        const int b = bOf[k];
        binned[b * CAPD + gbase[b] + (k - histEx[b])] = sorted[k];
    }
}

// ---------------------------------------------------------------------------
// K2: per-bucket counting sort fully in LDS, IN PLACE on the fixed-capacity
// region -> srcSorted (plain src ids) + s_arr/e_arr per node.
// 1024 threads (16 waves): 4x shallower latency-chained passes than the
// 256-thread version (build was TLP-starved: 196 blocks ~ 1/CU).
// ---------------------------------------------------------------------------
__global__ __launch_bounds__(1024) void bucket_csr_kernel(
        int* __restrict__ binned, const int* __restrict__ cursor,
        int* __restrict__ s_arr, int* __restrict__ e_arr) {
    __shared__ int lhist[512];
    __shared__ int lcur[512];
    __shared__ int sortedS[CAPD];        // 32 KB
    __shared__ int wsum[16], wexc[16];
    const int tid  = threadIdx.x;
    const int lane = tid & 63, wid = tid >> 6;
    const int b = blockIdx.x;
    const int n0 = b * 512;
    const int nb = min(512, NN - n0);
    const int lo = b * CAPD;
    const int cnt = min(cursor[b], CAPD);

    if (tid < 512) lhist[tid] = 0;
    __syncthreads();
    for (int k = tid; k < cnt; k += 1024)
        atomicAdd(&lhist[binned[lo + k] & 511], 1);
    __syncthreads();
    // scan 512 bins across 16 waves (threads >=512 contribute 0)
    const int v = (tid < 512) ? lhist[tid] : 0;
    int incl = v;
    #pragma unroll
    for (int off = 1; off < 64; off <<= 1) {
        int nup = __shfl_up(incl, off, 64);
        if (lane >= off) incl += nup;
    }
    if (lane == 63) wsum[wid] = incl;
    __syncthreads();
    if (tid == 0) {
        int r = 0;
        #pragma unroll
        for (int w = 0; w < 16; ++w) { wexc[w] = r; r += wsum[w]; }
    }
    __syncthreads();
    const int ex = wexc[wid] + incl - v;
    if (tid < 512) {
        if (tid < nb) { s_arr[n0 + tid] = lo + ex; e_arr[n0 + tid] = lo + ex + v; }
        lcur[tid] = ex;
    }
    __syncthreads();
    for (int k = tid; k < cnt; k += 1024) {
        const int rec = binned[lo + k];
        const int slot = atomicAdd(&lcur[rec & 511], 1);
        sortedS[slot] = rec >> 9;
    }
    __syncthreads();
    for (int k = tid; k < cnt; k += 1024) binned[lo + k] = sortedS[k];
}

// ---------------------------------------------------------------------------
// K3: fused gather(bf16) -> mean -> @W -> ELU -> h + BN-stat partials.
// Proven structure (grid-stride, quarter-wave/node, readlane GEMM; VGPR 60
// @ 89us). Single delta this round: masked uniform 8-wide gather rounds —
// every node runs ceil(deg/8) rounds of 8 independent loads (idx clamped,
// accumulate predicated), cutting dependent-latency steps 3+ -> 2 at deg 12.
// (Steal loops are known-poison: VGPR collapses to 24. Do not reintroduce.)
// ---------------------------------------------------------------------------
__global__ __launch_bounds__(256) void agg_gemm_kernel(
        const uint2* __restrict__ xb,           // [NN][16] uint2 (bf16 rows)
        const int*   __restrict__ s_arr,
        const int*   __restrict__ e_arr,
        const int*   __restrict__ srcSorted,
        const float* __restrict__ W,            // [D_IN, D_OUT] row-major
        float* __restrict__ h,
        float* __restrict__ stats) {            // [0..63]=sum, [64..127]=sumsq
    __shared__ float4 Wt2[16 * 64];             // [k0][c] = W[4k0..4k0+3][c]
    __shared__ float red[2][256];

    for (int i = threadIdx.x; i < D * D; i += 256) {
        const float val = W[i];
        const int k = i >> 6, cc = i & 63;
        ((float*)&Wt2[(k >> 2) * 64 + cc])[k & 3] = val;
    }
    __syncthreads();

    const int w    = threadIdx.x >> 6;          // wave slot 0..3
    const int lane = threadIdx.x & 63;
    const int q    = lane >> 4;                 // quarter-wave = node slot
    const int t    = lane & 15;                 // uint2 slot within row

    float s = 0.f, s2 = 0.f;
    const int nIter = NN / 16;                  // 6250, exact
    for (int it = blockIdx.x; it < nIter; it += gridDim.x) {
        const int node = it * 16 + w * 4 + q;
        const int e0 = s_arr[node], e1 = e_arr[node];
        float4 acc = make_float4(0.f, 0.f, 0.f, 0.f);
        for (int j = e0; j < e1; j += 8) {      // ceil(deg/8) uniform rounds
            #pragma unroll
            for (int u = 0; u < 8; ++u) {
                const int jj = j + u;
                const int sid = srcSorted[min(jj, e1 - 1)];  // always valid
                const uint2 a = xb[(size_t)sid * 16 + t];
                if (jj < e1) acc_bf16(acc, a);  // predicated accumulate
            }
        }
        const float deg = (float)(e1 - e0);

        // GEMM: 4 nodes per wave, broadcast via readlane (uniform lane ids)
        #pragma unroll
        for (int qq = 0; qq < 4; ++qq) {
            float hacc = 0.f;
            #pragma unroll
            for (int k0 = 0; k0 < 16; ++k0) {
                const float4 wv = Wt2[k0 * 64 + lane];
                const int srcL = qq * 16 + k0;
                hacc = fmaf(bcastf(acc.x, srcL), wv.x, hacc);
                hacc = fmaf(bcastf(acc.y, srcL), wv.y, hacc);
                hacc = fmaf(bcastf(acc.z, srcL), wv.z, hacc);
                hacc = fmaf(bcastf(acc.w, srcL), wv.w, hacc);
            }
            const float invq = 1.0f / fmaxf(bcastf(deg, qq * 16), 1.0f);
            hacc *= invq;                       // (agg*inv)@W == inv*(agg@W)
            const float hv = hacc > 0.f ? hacc : expm1f(hacc);
            const int nodeq = it * 16 + w * 4 + qq;
            h[(size_t)nodeq * 64 + lane] = hv;
            s  += hv;
            s2 += hv * hv;
        }
    }

    red[0][threadIdx.x] = s;
    red[1][threadIdx.x] = s2;
    __syncthreads();
    if (threadIdx.x < 64) {
        float ts  = red[0][threadIdx.x] + red[0][threadIdx.x + 64] +
                    red[0][threadIdx.x + 128] + red[0][threadIdx.x + 192];
        float ts2 = red[1][threadIdx.x] + red[1][threadIdx.x + 64] +
                    red[1][threadIdx.x + 128] + red[1][threadIdx.x + 192];
        atomicAdd(&stats[threadIdx.x],      ts);
        atomicAdd(&stats[64 + threadIdx.x], ts2);
    }
}

// ---------------------------------------------------------------------------
// K4: BatchNorm finalize, float4-vectorized streaming.
// ---------------------------------------------------------------------------
__global__ __launch_bounds__(256) void bn_kernel(
        const float4* __restrict__ h,
        const float*  __restrict__ stats,
        const float*  __restrict__ gamma,
        const float*  __restrict__ beta,
        float4* __restrict__ out) {
    int gid = blockIdx.x * 256 + threadIdx.x;     // over NN*D/4 exact
    const int c0 = (gid & 15) * 4;
    const float4 v = h[gid];
    float4 r;
    const float* vv = (const float*)&v;
    float* rr = (float*)&r;
    #pragma unroll
    for (int k = 0; k < 4; ++k) {
        const int c = c0 + k;
        const float mu  = stats[c] * (1.0f / NN);
        const float var = stats[64 + c] * (1.0f / NN) - mu * mu;
        const float is  = rsqrtf(var + BN_EPS);
        rr[k] = (vv[k] - mu) * is * gamma[c] + beta[c];
    }
    out[gid] = r;
}

extern "C" void kernel_launch(void* const* d_in, const int* in_sizes, int n_in,
                              void* d_out, int out_size, void* d_ws, size_t ws_size,
                              hipStream_t stream) {
    const float* x     = (const float*)d_in[0];
    const int*   ei    = (const int*)  d_in[1];
    const float* W     = (const float*)d_in[2];
    const float* gamma = (const float*)d_in[3];
    const float* beta  = (const float*)d_in[4];
    float* out = (float*)d_out;

    // workspace layout (4B units):
    // [buf NN*D][stats 128][cursor 256][s_arr NN+pad][e_arr NN+pad]
    // [srcSorted NB*CAPD][xb NN*16 uint2]
    float* buf       = (float*)d_ws;
    float* stats     = buf + (size_t)NN * D;
    int*   cursor    = (int*)(stats + 128);
    int*   s_arr     = cursor + 256;
    int*   e_arr     = s_arr + NN + 352;             // pad to keep 8B align
    int*   srcSorted = e_arr + NN + 352;
    uint2* xb        = (uint2*)(srcSorted + (size_t)NB * CAPD);

    // zero stats + bucket cursors (contiguous)
    hipMemsetAsync(stats, 0, 384 * sizeof(int), stream);

    cvt_binsort_kernel<<<NCVT + NCHUNK, 256, 0, stream>>>(
        (const float4*)x, xb, ei, ei + NE, cursor, srcSorted);
    bucket_csr_kernel <<<NB, 1024, 0, stream>>>(srcSorted, cursor, s_arr, e_arr);
    agg_gemm_kernel   <<<2048, 256, 0, stream>>>(
        xb, s_arr, e_arr, srcSorted, W, buf, stats);
    bn_kernel         <<<NN * D / 4 / 256, 256, 0, stream>>>(
        (const float4*)buf, stats, gamma, beta, (float4*)out);
}